// Round 13
// baseline (233.580 us; speedup 1.0000x reference)
//
#include <hip/hip_runtime.h>
#include <hip/hip_bf16.h>
#include <cstdint>

static constexpr int B_  = 8;
static constexpr int C_  = 64;
static constexpr int N_  = 65536;
static constexpr int Rr  = 32;
static constexpr int R3  = Rr * Rr * Rr;        // 32768 = 2^15
static constexpr int PBLK  = 16;                // partial blocks per (b,axis) for mean
static constexpr int PBLKM = 64;                // partial blocks per batch for max
static constexpr int PTS_PER_BLK  = N_ / PBLK;  // 4096
static constexpr int PTS_PER_BLKM = N_ / PBLKM; // 1024
static constexpr int NTILES = B_ * (N_ / 64);   // 8192 ftN tiles

__device__ __forceinline__ float bf2f(unsigned short u) {
    union { unsigned int i; float f; } x;
    x.i = ((unsigned int)u) << 16;
    return x.f;
}
__device__ __forceinline__ unsigned short f2bf(float f) {
    __hip_bfloat16 h = (__hip_bfloat16)f;       // RNE
    return *reinterpret_cast<unsigned short*>(&h);
}

// ---------------- kernel A: ftN build (natural order) + partial mean + zero counts ----------------
// block ranges: [0, NTILES) ftN transpose tiles; [NTILES, NTILES+384) pmean; last 256 zero counts.
__global__ void ftn_pmean_zero_kernel(const float* __restrict__ features,
                                      const float* __restrict__ coords,
                                      float* __restrict__ pmean,
                                      int4* __restrict__ counts4,
                                      int* __restrict__ n_occ,
                                      __hip_bfloat16* __restrict__ ftN) {
    int bid = blockIdx.x;
    const int t = threadIdx.x;
    if (bid < NTILES) {
        // ---- [C][N] f32 -> [N][C] bf16, both sides coalesced ----
        const int b  = bid >> 10;
        const int n0 = (bid & 1023) << 6;
        __shared__ unsigned short tileS[64][66];   // [channel][point], +2 pad
        const int g  = t & 15;                     // float4 lane within channel row
        const int c0 = t >> 4;
        #pragma unroll
        for (int it = 0; it < 4; ++it) {
            const int c = it * 16 + c0;
            const float4 v = *(const float4*)(features + ((size_t)b * C_ + c) * N_ + n0 + g * 4);
            ushort4 u;
            u.x = f2bf(v.x); u.y = f2bf(v.y); u.z = f2bf(v.z); u.w = f2bf(v.w);
            *(ushort4*)&tileS[c][g * 4] = u;
        }
        __syncthreads();
        #pragma unroll
        for (int p = 0; p < 2; ++p) {
            const int oi = p * 256 + t;            // 0..511
            const int j  = oi >> 3;                // point row 0..63
            const int cb = (oi & 7) * 8;           // 8-channel group
            unsigned int w0 = (unsigned int)tileS[cb + 0][j] | ((unsigned int)tileS[cb + 1][j] << 16);
            unsigned int w1 = (unsigned int)tileS[cb + 2][j] | ((unsigned int)tileS[cb + 3][j] << 16);
            unsigned int w2 = (unsigned int)tileS[cb + 4][j] | ((unsigned int)tileS[cb + 5][j] << 16);
            unsigned int w3 = (unsigned int)tileS[cb + 6][j] | ((unsigned int)tileS[cb + 7][j] << 16);
            *(uint4*)((unsigned short*)ftN + ((size_t)b * N_ + n0 + j) * C_ + cb) =
                make_uint4(w0, w1, w2, w3);
        }
        return;
    }
    bid -= NTILES;
    if (bid < B_ * 3 * PBLK) {
        // ---- partial mean ----
        const int blk = bid & (PBLK - 1);
        const int ba  = bid / PBLK;
        const float4* p = (const float4*)(coords + (size_t)ba * N_ + (size_t)blk * PTS_PER_BLK);
        float s = 0.f;
        #pragma unroll
        for (int k = 0; k < PTS_PER_BLK / 4 / 256; ++k) {   // 4 iters
            float4 v = p[k * 256 + t];
            s += (v.x + v.y) + (v.z + v.w);
        }
        #pragma unroll
        for (int off = 32; off >= 1; off >>= 1) s += __shfl_down(s, off, 64);
        __shared__ float sm[4];
        if ((t & 63) == 0) sm[t >> 6] = s;
        __syncthreads();
        if (t == 0) pmean[bid] = sm[0] + sm[1] + sm[2] + sm[3];
        return;
    }
    bid -= B_ * 3 * PBLK;
    // ---- zero counts + n_occ ----
    counts4[bid * 256 + t] = make_int4(0, 0, 0, 0);
    if (bid == 0 && t == 0) *n_occ = 0;
}

// ---------------- kernel B: partial max of centered norm^2 (512 blocks) ----------------
__global__ void partial_max_kernel(const float* __restrict__ coords,
                                   const float* __restrict__ pmean,
                                   float* __restrict__ pmax) {
    const int blk = blockIdx.x & (PBLKM - 1);
    const int b   = blockIdx.x / PBLKM;
    __shared__ float msh[3];
    if (threadIdx.x == 0) {
        #pragma unroll
        for (int a = 0; a < 3; ++a) {
            float t = 0.f;
            #pragma unroll
            for (int k = 0; k < PBLK; ++k) t += pmean[(b * 3 + a) * PBLK + k];
            msh[a] = t / (float)N_;
        }
    }
    __syncthreads();
    const float mx = msh[0], my = msh[1], mz = msh[2];
    const float4* px = (const float4*)(coords + (size_t)b * 3 * N_ + (size_t)blk * PTS_PER_BLKM);
    const float4* py = px + N_ / 4;
    const float4* pz = px + 2 * (N_ / 4);
    const int i = threadIdx.x;           // exactly one float4 per thread
    float4 x = px[i], y = py[i], z = pz[i];
    float m = 0.f;
    {
        float x0 = x.x - mx, y0 = y.x - my, z0 = z.x - mz;
        float x1 = x.y - mx, y1 = y.y - my, z1 = z.y - mz;
        float x2 = x.z - mx, y2 = y.z - my, z2 = z.z - mz;
        float x3 = x.w - mx, y3 = y.w - my, z3 = z.w - mz;
        m = fmaxf(m, x0 * x0 + y0 * y0 + z0 * z0);
        m = fmaxf(m, x1 * x1 + y1 * y1 + z1 * z1);
        m = fmaxf(m, x2 * x2 + y2 * y2 + z2 * z2);
        m = fmaxf(m, x3 * x3 + y3 * y3 + z3 * z3);
    }
    #pragma unroll
    for (int off = 32; off >= 1; off >>= 1) m = fmaxf(m, __shfl_down(m, off, 64));
    __shared__ float sm[4];
    if ((threadIdx.x & 63) == 0) sm[threadIdx.x >> 6] = m;
    __syncthreads();
    if (threadIdx.x == 0)
        pmax[blockIdx.x] = fmaxf(fmaxf(sm[0], sm[1]), fmaxf(sm[2], sm[3]));
}

// ---------------- kernel C: voxelize: nc_out + flat ids + int counts ----------------
__global__ void voxelize_kernel(const float* __restrict__ coords,
                                const float* __restrict__ pmean,
                                const float* __restrict__ pmax,
                                float* __restrict__ nc_out,     // [B,3,N]
                                int* __restrict__ flat_out,     // [B,N]
                                int* __restrict__ counts) {     // [B,R3], pre-zeroed
    const int idx = blockIdx.x * blockDim.x + threadIdx.x;
    const int b = idx >> 16;            // block spans one b (256 | N)
    const int n = idx & (N_ - 1);
    __shared__ float par[4];            // mx,my,mz,denom
    if (threadIdx.x == 0) {
        #pragma unroll
        for (int a = 0; a < 3; ++a) {
            float t = 0.f;
            #pragma unroll
            for (int k = 0; k < PBLK; ++k) t += pmean[(b * 3 + a) * PBLK + k];
            par[a] = t / (float)N_;
        }
        float mm = 0.f;
        #pragma unroll
        for (int k = 0; k < PBLKM; ++k) mm = fmaxf(mm, pmax[b * PBLKM + k]);
        par[3] = 2.0f * sqrtf(mm);      // EPS == 0; sqrt(max n2) == max norm
    }
    __syncthreads();
    const float* pc = coords + (size_t)b * 3 * N_;
    const float denom = par[3];
    int flat = 0;
    #pragma unroll
    for (int a = 0; a < 3; ++a) {
        float v = (pc[(size_t)a * N_ + n] - par[a]) / denom + 0.5f;
        v = v * (float)Rr;
        v = fminf(fmaxf(v, 0.0f), (float)(Rr - 1));
        nc_out[(size_t)b * 3 * N_ + (size_t)a * N_ + n] = v;
        flat = flat * Rr + (int)rintf(v);   // round half to even == jnp.round
    }
    flat_out[idx] = flat;
    atomicAdd(&counts[b * R3 + flat], 1);
}

// ---------------- kernel D: per-batch scan + compaction, shfl-based (2 barriers) ----------------
__global__ void scan_compact_kernel(const int* __restrict__ counts,
                                    int* __restrict__ cursor,
                                    int4* __restrict__ clist,
                                    int* __restrict__ n_occ) {
    const int b = blockIdx.x;          // [0,B)
    const int t = threadIdx.x;         // 1024 threads
    const int lane = t & 63, wv = t >> 6;    // 16 waves
    constexpr int PER = R3 / 1024;     // 32
    int local[PER];
    const int4* c4 = (const int4*)(counts + b * R3);
    int s = 0, nz = 0;
    #pragma unroll
    for (int k = 0; k < PER / 4; ++k) {      // 8 int4 loads
        const int4 v = c4[t * (PER / 4) + k];
        local[k * 4 + 0] = v.x; local[k * 4 + 1] = v.y;
        local[k * 4 + 2] = v.z; local[k * 4 + 3] = v.w;
        s  += v.x + v.y + v.z + v.w;
        nz += (v.x > 0) + (v.y > 0) + (v.z > 0) + (v.w > 0);
    }
    const int s_own = s, nz_own = nz;
    #pragma unroll
    for (int off = 1; off < 64; off <<= 1) {
        const int vs = __shfl_up(s, off, 64);
        const int vn = __shfl_up(nz, off, 64);
        if (lane >= off) { s += vs; nz += vn; }
    }
    __shared__ int wsum[16], wnz[16], woffs[16], woffn[16];
    __shared__ int basesh;
    if (lane == 63) { wsum[wv] = s; wnz[wv] = nz; }
    __syncthreads();
    if (t < 16) {
        const int as = wsum[t], an = wnz[t];
        int is = as, in_ = an;
        #pragma unroll
        for (int off = 1; off < 16; off <<= 1) {
            const int vs = __shfl_up(is, off, 16);
            const int vn = __shfl_up(in_, off, 16);
            if (t >= off) { is += vs; in_ += vn; }
        }
        woffs[t] = is - as;
        woffn[t] = in_ - an;
        if (t == 15) basesh = atomicAdd(n_occ, in_);
    }
    __syncthreads();
    int run  = woffs[wv] + (s - s_own);
    int slot = basesh + woffn[wv] + (nz - nz_own);
    int* cur = cursor + b * R3 + t * PER;
    #pragma unroll
    for (int k = 0; k < PER; ++k) {
        cur[k] = run;
        if (local[k] > 0) clist[slot++] = make_int4(b * R3 + t * PER + k, run, local[k], 0);
        run += local[k];
    }
}

// ---------------- kernel E: assign sorted order: sorted_n[b][pos] = n ----------------
__global__ void scatter_ids_kernel(const int* __restrict__ flat,
                                   int* __restrict__ cursor,
                                   int* __restrict__ sorted_n) {   // [B,N]
    const int idx = blockIdx.x * blockDim.x + threadIdx.x;
    if (idx >= B_ * N_) return;
    const int b = idx >> 16;
    const int n = idx & (N_ - 1);
    const int f = flat[idx];
    const int p = atomicAdd(&cursor[b * R3 + f], 1);
    sorted_n[b * N_ + p] = n;   // same-segment writes are adjacent -> L2 coalesces
}

// ---------------- kernel F: per-voxel gather-sum from ftN (random 128B READS) ----------------
__global__ void voxel_sum_gather_kernel(const __hip_bfloat16* __restrict__ ftN, // [B,N,C]
                                        const int* __restrict__ sorted_n,       // [B,N]
                                        const int4* __restrict__ clist,
                                        const int* __restrict__ n_occ,
                                        float* __restrict__ acc) {              // [B,R3,C]
    const int lane = threadIdx.x & 63;
    const int gw = blockIdx.x * (blockDim.x >> 6) + (threadIdx.x >> 6);
    const int nw = gridDim.x * (blockDim.x >> 6);
    const int tot = *n_occ;
    const int sub = lane >> 4;
    const int g   = lane & 15;
    for (int e = gw; e < tot; e += nw) {
        const int4 ent = clist[e];           // wave-uniform broadcast
        const int wid = ent.x, start = ent.y, cnt = ent.z;
        const int b = wid >> 15;             // R3 = 2^15
        const int* sn = sorted_n + b * N_ + start;
        const unsigned short* fb = (const unsigned short*)ftN + (size_t)b * N_ * C_ + g * 4;
        float a0 = 0.f, a1 = 0.f, a2 = 0.f, a3 = 0.f;
        for (int t = sub; t < cnt; t += 4) {
            const int n = sn[t];             // broadcast within 16-lane g-group
            const ushort4 u = *(const ushort4*)(fb + (size_t)n * C_);
            a0 += bf2f(u.x); a1 += bf2f(u.y); a2 += bf2f(u.z); a3 += bf2f(u.w);
        }
        #pragma unroll
        for (int off = 16; off <= 32; off <<= 1) {
            a0 += __shfl_xor(a0, off, 64);
            a1 += __shfl_xor(a1, off, 64);
            a2 += __shfl_xor(a2, off, 64);
            a3 += __shfl_xor(a3, off, 64);
        }
        if (sub == 0) {
            *(float4*)(acc + (size_t)wid * C_ + g * 4) = make_float4(a0, a1, a2, a3);
        }
    }
}

// ---------------- kernel G: transpose acc[b][v][c]/max(cnt,1) -> out[b][c][v] ----------------
__global__ void transpose_finalize_kernel(const float* __restrict__ acc,
                                          const int* __restrict__ counts,
                                          float* __restrict__ out) {
    const int chunk = blockIdx.x;                 // [0, B * R3/64)
    const int b  = chunk >> 9;                    // R3/64 = 512 per batch
    const int v0 = (chunk & 511) * 64;
    __shared__ float tile[64][65];
    __shared__ float cnt_s[64];
    __shared__ int   occ[64];
    const int lane = threadIdx.x & 63, row0 = threadIdx.x >> 6;
    if (threadIdx.x < 64) {
        const int c = counts[b * R3 + v0 + threadIdx.x];
        occ[threadIdx.x]   = c;
        cnt_s[threadIdx.x] = fmaxf((float)c, 1.0f);
    }
    __syncthreads();
    #pragma unroll
    for (int it = 0; it < 16; ++it) {
        const int vi = row0 + it * 4;             // wave-uniform row
        tile[vi][lane] = occ[vi] ? acc[((size_t)(b * R3 + v0 + vi)) * C_ + lane] : 0.f;
    }
    __syncthreads();
    #pragma unroll
    for (int it = 0; it < 16; ++it) {
        const int c = row0 + it * 4;
        out[((size_t)b * C_ + c) * R3 + v0 + lane] = tile[lane][c] / cnt_s[lane];
    }
}

// ============ FALLBACK PATH (round-1 style) ============
__global__ void mean_kernel(const float* __restrict__ coords,
                            float* __restrict__ mean_out) {
    const int ba = blockIdx.x;
    const float* p = coords + (size_t)ba * N_;
    float s = 0.f;
    for (int i = threadIdx.x; i < N_; i += blockDim.x) s += p[i];
    #pragma unroll
    for (int off = 32; off >= 1; off >>= 1) s += __shfl_down(s, off, 64);
    __shared__ float sm[4];
    if ((threadIdx.x & 63) == 0) sm[threadIdx.x >> 6] = s;
    __syncthreads();
    if (threadIdx.x == 0) mean_out[ba] = (sm[0] + sm[1] + sm[2] + sm[3]) / (float)N_;
}

__global__ void maxnorm_kernel(const float* __restrict__ coords,
                               const float* __restrict__ mean,
                               float* __restrict__ maxn) {
    const int b = blockIdx.x;
    const float* p = coords + (size_t)b * 3 * N_;
    const float mx = mean[b * 3 + 0], my = mean[b * 3 + 1], mz = mean[b * 3 + 2];
    float m = 0.f;
    for (int i = threadIdx.x; i < N_; i += blockDim.x) {
        const float x = p[i] - mx, y = p[N_ + i] - my, z = p[2 * N_ + i] - mz;
        m = fmaxf(m, x * x + y * y + z * z);
    }
    #pragma unroll
    for (int off = 32; off >= 1; off >>= 1) m = fmaxf(m, __shfl_down(m, off, 64));
    __shared__ float sm[16];
    if ((threadIdx.x & 63) == 0) sm[threadIdx.x >> 6] = m;
    __syncthreads();
    if (threadIdx.x == 0) {
        float t = sm[0];
        const int nw = blockDim.x >> 6;
        for (int w = 1; w < nw; ++w) t = fmaxf(t, sm[w]);
        maxn[b] = sqrtf(t);
    }
}

__global__ void scatter_kernel(const float* __restrict__ coords,
                               const float* __restrict__ features,
                               const float* __restrict__ mean,
                               const float* __restrict__ maxn,
                               float* __restrict__ out,
                               float* __restrict__ nc_out,
                               float* __restrict__ counts) {
    const int idx = blockIdx.x * blockDim.x + threadIdx.x;
    if (idx >= B_ * N_) return;
    const int b = idx >> 16;
    const int n = idx & (N_ - 1);
    const float* pc = coords + (size_t)b * 3 * N_;
    const float denom = 2.0f * maxn[b];
    int flat = 0;
    #pragma unroll
    for (int a = 0; a < 3; ++a) {
        float v = (pc[(size_t)a * N_ + n] - mean[b * 3 + a]) / denom + 0.5f;
        v = v * (float)Rr;
        v = fminf(fmaxf(v, 0.0f), (float)(Rr - 1));
        nc_out[(size_t)b * 3 * N_ + (size_t)a * N_ + n] = v;
        flat = flat * Rr + (int)rintf(v);
    }
    atomicAdd(&counts[b * R3 + flat], 1.0f);
    const float* pf = features + (size_t)b * C_ * N_ + n;
    float* po = out + (size_t)b * C_ * R3 + flat;
    #pragma unroll 4
    for (int c = 0; c < C_; ++c) atomicAdd(po + (size_t)c * R3, pf[(size_t)c * N_]);
}

__global__ void finalize_kernel(float* __restrict__ out,
                                const float* __restrict__ counts) {
    const int idx = blockIdx.x * blockDim.x + threadIdx.x;
    if (idx >= B_ * C_ * R3) return;
    const int b = idx / (C_ * R3);
    const int v = idx & (R3 - 1);
    out[idx] = out[idx] / fmaxf(counts[b * R3 + v], 1.0f);
}

extern "C" void kernel_launch(void* const* d_in, const int* in_sizes, int n_in,
                              void* d_out, int out_size, void* d_ws, size_t ws_size,
                              hipStream_t stream) {
    const float* features = (const float*)d_in[0];   // [B,C,N]
    const float* coords   = (const float*)d_in[1];   // [B,3,N]

    float* out    = (float*)d_out;                   // [B,C,R,R,R]
    float* nc_out = out + (size_t)B_ * C_ * R3;      // [B,3,N]

    const size_t accB   = (size_t)B_ * R3 * C_ * sizeof(float);  // 64 MiB
    const size_t cntB   = (size_t)B_ * R3 * sizeof(int);         // 1 MiB
    const size_t curB   = cntB;
    const size_t flatB  = (size_t)B_ * N_ * sizeof(int);         // 2 MiB
    const size_t snB    = flatB;                                 // 2 MiB
    const size_t clistB = (size_t)B_ * R3 * sizeof(int4);        // 4 MiB (worst case)
    const size_t smallB = 16384;                                 // n_occ + pmean + pmax
    const size_t ftnB   = (size_t)B_ * N_ * C_ * sizeof(__hip_bfloat16);  // 64 MiB

    const size_t need = accB + cntB + curB + flatB + snB + clistB + smallB + ftnB;
    const int pts = B_ * N_;

    if (ws_size >= need) {
        // -------- sorted-gather fast path (bf16 ftN natural order, gather-sum) --------
        char* w = (char*)d_ws;
        float* acc      = (float*)w;               w += accB;    // [B,R3,C] (no memset)
        int*   counts   = (int*)w;                 w += cntB;    // [B,R3]
        int*   cursor   = (int*)w;                 w += curB;
        int*   flat     = (int*)w;                 w += flatB;   // [B,N]
        int*   sorted_n = (int*)w;                 w += snB;     // [B,N]
        int4*  clist    = (int4*)w;                w += clistB;
        int*   n_occ    = (int*)w;
        float* pmean    = (float*)(w + 16);        // [B*3*PBLK]
        float* pmax     = pmean + B_ * 3 * PBLK;   // [B*PBLKM]
        w += smallB;
        __hip_bfloat16* ftN = (__hip_bfloat16*)w;  // [B,N,C]

        ftn_pmean_zero_kernel<<<NTILES + B_ * 3 * PBLK + 256, 256, 0, stream>>>(
            features, coords, pmean, (int4*)counts, n_occ, ftN);
        partial_max_kernel<<<B_ * PBLKM, 256, 0, stream>>>(coords, pmean, pmax);
        voxelize_kernel<<<pts / 256, 256, 0, stream>>>(
            coords, pmean, pmax, nc_out, flat, counts);
        scan_compact_kernel<<<B_, 1024, 0, stream>>>(counts, cursor, clist, n_occ);
        scatter_ids_kernel<<<pts / 256, 256, 0, stream>>>(flat, cursor, sorted_n);
        voxel_sum_gather_kernel<<<1024, 256, 0, stream>>>(ftN, sorted_n, clist, n_occ, acc);
        transpose_finalize_kernel<<<B_ * (R3 / 64), 256, 0, stream>>>(acc, counts, out);
    } else {
        // -------- fallback path --------
        float* counts = (float*)d_ws;
        float* mean   = counts + (size_t)B_ * R3;
        float* maxn   = mean + B_ * 3;

        hipMemsetAsync(d_out, 0, (size_t)B_ * C_ * R3 * sizeof(float), stream);
        hipMemsetAsync(d_ws, 0, ((size_t)B_ * R3 + B_ * 3 + B_) * sizeof(float), stream);

        mean_kernel<<<B_ * 3, 256, 0, stream>>>(coords, mean);
        maxnorm_kernel<<<B_, 1024, 0, stream>>>(coords, mean, maxn);
        scatter_kernel<<<(pts + 255) / 256, 256, 0, stream>>>(
            coords, features, mean, maxn, out, nc_out, counts);
        finalize_kernel<<<(B_ * C_ * R3 + 255) / 256, 256, 0, stream>>>(out, counts);
    }
}

// Round 15
// 165.810 us; speedup vs baseline: 1.4087x; 1.4087x over previous
//
#include <hip/hip_runtime.h>
#include <hip/hip_bf16.h>
#include <cstdint>

static constexpr int B_  = 8;
static constexpr int C_  = 64;
static constexpr int N_  = 65536;
static constexpr int Rr  = 32;
static constexpr int R3  = Rr * Rr * Rr;        // 32768 = 2^15
static constexpr int PBLK  = 16;                // partial blocks per (b,axis) for mean
static constexpr int PBLKM = 64;                // partial blocks per batch for max
static constexpr int PTS_PER_BLK  = N_ / PBLK;  // 4096
static constexpr int PTS_PER_BLKM = N_ / PBLKM; // 1024

typedef float f32x4 __attribute__((ext_vector_type(4)));   // native vector: OK for NT builtins

__device__ __forceinline__ float bf2f(unsigned short u) {
    union { unsigned int i; float f; } x;
    x.i = ((unsigned int)u) << 16;
    return x.f;
}
__device__ __forceinline__ unsigned short f2bf(float f) {
    __hip_bfloat16 h = (__hip_bfloat16)f;       // RNE
    return *reinterpret_cast<unsigned short*>(&h);
}

// ---------------- kernel A: partial mean (blocks 0..383) + zero counts/n_occ ----------------
__global__ void pmean_zero_kernel(const float* __restrict__ coords,
                                  float* __restrict__ pmean,
                                  int4* __restrict__ counts4,   // B*R3 ints = 65536 int4
                                  int* __restrict__ n_occ) {
    if (blockIdx.x >= B_ * 3 * PBLK) {
        const int zb = blockIdx.x - B_ * 3 * PBLK;     // 0..255
        counts4[zb * 256 + threadIdx.x] = make_int4(0, 0, 0, 0);
        if (zb == 0 && threadIdx.x == 0) *n_occ = 0;
        return;
    }
    const int blk = blockIdx.x & (PBLK - 1);
    const int ba  = blockIdx.x / PBLK;
    const float4* p = (const float4*)(coords + (size_t)ba * N_ + (size_t)blk * PTS_PER_BLK);
    float s = 0.f;
    #pragma unroll
    for (int k = 0; k < PTS_PER_BLK / 4 / 256; ++k) {   // 4 iters
        float4 v = p[k * 256 + threadIdx.x];
        s += (v.x + v.y) + (v.z + v.w);
    }
    #pragma unroll
    for (int off = 32; off >= 1; off >>= 1) s += __shfl_down(s, off, 64);
    __shared__ float sm[4];
    if ((threadIdx.x & 63) == 0) sm[threadIdx.x >> 6] = s;
    __syncthreads();
    if (threadIdx.x == 0) pmean[blockIdx.x] = sm[0] + sm[1] + sm[2] + sm[3];
}

// ---------------- kernel B: partial max of centered norm^2 (512 blocks) ----------------
__global__ void partial_max_kernel(const float* __restrict__ coords,
                                   const float* __restrict__ pmean,
                                   float* __restrict__ pmax) {
    const int blk = blockIdx.x & (PBLKM - 1);
    const int b   = blockIdx.x / PBLKM;
    __shared__ float msh[3];
    if (threadIdx.x == 0) {
        #pragma unroll
        for (int a = 0; a < 3; ++a) {
            float t = 0.f;
            #pragma unroll
            for (int k = 0; k < PBLK; ++k) t += pmean[(b * 3 + a) * PBLK + k];
            msh[a] = t / (float)N_;
        }
    }
    __syncthreads();
    const float mx = msh[0], my = msh[1], mz = msh[2];
    const float4* px = (const float4*)(coords + (size_t)b * 3 * N_ + (size_t)blk * PTS_PER_BLKM);
    const float4* py = px + N_ / 4;
    const float4* pz = px + 2 * (N_ / 4);
    const int i = threadIdx.x;           // exactly one float4 per thread
    float4 x = px[i], y = py[i], z = pz[i];
    float m = 0.f;
    {
        float x0 = x.x - mx, y0 = y.x - my, z0 = z.x - mz;
        float x1 = x.y - mx, y1 = y.y - my, z1 = z.y - mz;
        float x2 = x.z - mx, y2 = y.z - my, z2 = z.z - mz;
        float x3 = x.w - mx, y3 = y.w - my, z3 = z.w - mz;
        m = fmaxf(m, x0 * x0 + y0 * y0 + z0 * z0);
        m = fmaxf(m, x1 * x1 + y1 * y1 + z1 * z1);
        m = fmaxf(m, x2 * x2 + y2 * y2 + z2 * z2);
        m = fmaxf(m, x3 * x3 + y3 * y3 + z3 * z3);
    }
    #pragma unroll
    for (int off = 32; off >= 1; off >>= 1) m = fmaxf(m, __shfl_down(m, off, 64));
    __shared__ float sm[4];
    if ((threadIdx.x & 63) == 0) sm[threadIdx.x >> 6] = m;
    __syncthreads();
    if (threadIdx.x == 0)
        pmax[blockIdx.x] = fmaxf(fmaxf(sm[0], sm[1]), fmaxf(sm[2], sm[3]));
}

// ---------------- kernel C: voxelize: nc_out + flat ids + int counts ----------------
__global__ void voxelize_kernel(const float* __restrict__ coords,
                                const float* __restrict__ pmean,
                                const float* __restrict__ pmax,
                                float* __restrict__ nc_out,     // [B,3,N]
                                int* __restrict__ flat_out,     // [B,N]
                                int* __restrict__ counts) {     // [B,R3], pre-zeroed
    const int idx = blockIdx.x * blockDim.x + threadIdx.x;
    const int b = idx >> 16;            // block spans one b (256 | N)
    const int n = idx & (N_ - 1);
    __shared__ float par[4];            // mx,my,mz,denom
    if (threadIdx.x == 0) {
        #pragma unroll
        for (int a = 0; a < 3; ++a) {
            float t = 0.f;
            #pragma unroll
            for (int k = 0; k < PBLK; ++k) t += pmean[(b * 3 + a) * PBLK + k];
            par[a] = t / (float)N_;
        }
        float mm = 0.f;
        #pragma unroll
        for (int k = 0; k < PBLKM; ++k) mm = fmaxf(mm, pmax[b * PBLKM + k]);
        par[3] = 2.0f * sqrtf(mm);      // EPS == 0; sqrt(max n2) == max norm
    }
    __syncthreads();
    const float* pc = coords + (size_t)b * 3 * N_;
    const float denom = par[3];
    int flat = 0;
    #pragma unroll
    for (int a = 0; a < 3; ++a) {
        float v = (pc[(size_t)a * N_ + n] - par[a]) / denom + 0.5f;
        v = v * (float)Rr;
        v = fminf(fmaxf(v, 0.0f), (float)(Rr - 1));
        nc_out[(size_t)b * 3 * N_ + (size_t)a * N_ + n] = v;
        flat = flat * Rr + (int)rintf(v);   // round half to even == jnp.round
    }
    flat_out[idx] = flat;
    atomicAdd(&counts[b * R3 + flat], 1);
}

// ---------------- kernel D: per-batch scan + compaction, shfl-based (2 barriers) ----------------
__global__ void scan_compact_kernel(const int* __restrict__ counts,
                                    int* __restrict__ cursor,
                                    int4* __restrict__ clist,
                                    int* __restrict__ n_occ) {
    const int b = blockIdx.x;          // [0,B)
    const int t = threadIdx.x;         // 1024 threads
    const int lane = t & 63, wv = t >> 6;    // 16 waves
    constexpr int PER = R3 / 1024;     // 32
    int local[PER];
    const int4* c4 = (const int4*)(counts + b * R3);
    int s = 0, nz = 0;
    #pragma unroll
    for (int k = 0; k < PER / 4; ++k) {      // 8 int4 loads
        const int4 v = c4[t * (PER / 4) + k];
        local[k * 4 + 0] = v.x; local[k * 4 + 1] = v.y;
        local[k * 4 + 2] = v.z; local[k * 4 + 3] = v.w;
        s  += v.x + v.y + v.z + v.w;
        nz += (v.x > 0) + (v.y > 0) + (v.z > 0) + (v.w > 0);
    }
    const int s_own = s, nz_own = nz;
    #pragma unroll
    for (int off = 1; off < 64; off <<= 1) {
        const int vs = __shfl_up(s, off, 64);
        const int vn = __shfl_up(nz, off, 64);
        if (lane >= off) { s += vs; nz += vn; }
    }
    __shared__ int wsum[16], wnz[16], woffs[16], woffn[16];
    __shared__ int basesh;
    if (lane == 63) { wsum[wv] = s; wnz[wv] = nz; }
    __syncthreads();
    if (t < 16) {
        const int as = wsum[t], an = wnz[t];
        int is = as, in_ = an;
        #pragma unroll
        for (int off = 1; off < 16; off <<= 1) {
            const int vs = __shfl_up(is, off, 16);
            const int vn = __shfl_up(in_, off, 16);
            if (t >= off) { is += vs; in_ += vn; }
        }
        woffs[t] = is - as;
        woffn[t] = in_ - an;
        if (t == 15) basesh = atomicAdd(n_occ, in_);
    }
    __syncthreads();
    int run  = woffs[wv] + (s - s_own);
    int slot = basesh + woffn[wv] + (nz - nz_own);
    int* cur = cursor + b * R3 + t * PER;
    #pragma unroll
    for (int k = 0; k < PER; ++k) {
        cur[k] = run;
        if (local[k] > 0) clist[slot++] = make_int4(b * R3 + t * PER + k, run, local[k], 0);
        run += local[k];
    }
}

// ---------------- kernel E: fused pos-assign + transpose into sorted order (bf16) ----------------
// features loads are NON-TEMPORAL (read-once stream) -> keeps L2 free for ftS
// writes, which kernel F re-reads.
__global__ void sorted_transpose_ids_kernel(const float* __restrict__ features,
                                            const int* __restrict__ flat,
                                            int* __restrict__ cursor,
                                            __hip_bfloat16* __restrict__ ftS) {
    const int tile = blockIdx.x & 1023;   // N/64 tiles per batch
    const int b    = blockIdx.x >> 10;
    const int n0   = tile * 64;
    __shared__ unsigned short tileS[64][66];   // [channel][point], +2 pad
    __shared__ int pos_s[64];
    const int t = threadIdx.x;
    if (t < 64) {
        const int f = flat[b * N_ + n0 + t];
        pos_s[t] = atomicAdd(&cursor[b * R3 + f], 1);
    }
    const int g  = t & 15;           // 16 float4 lanes per row
    const int c0 = t >> 4;           // 0..15
    #pragma unroll
    for (int it = 0; it < 4; ++it) {
        const int c = it * 16 + c0;
        const f32x4 v = __builtin_nontemporal_load(
            (const f32x4*)(features + ((size_t)b * C_ + c) * N_ + n0 + g * 4));
        ushort4 u;
        u.x = f2bf(v.x); u.y = f2bf(v.y); u.z = f2bf(v.z); u.w = f2bf(v.w);
        *(ushort4*)&tileS[c][g * 4] = u;
    }
    __syncthreads();
    #pragma unroll
    for (int p = 0; p < 2; ++p) {
        const int oi = p * 256 + t;          // 0..511
        const int j  = oi >> 3;              // point row 0..63
        const int o  = oi & 7;               // 8-channel group
        const int cb = o * 8;
        unsigned int w0 = (unsigned int)tileS[cb + 0][j] | ((unsigned int)tileS[cb + 1][j] << 16);
        unsigned int w1 = (unsigned int)tileS[cb + 2][j] | ((unsigned int)tileS[cb + 3][j] << 16);
        unsigned int w2 = (unsigned int)tileS[cb + 4][j] | ((unsigned int)tileS[cb + 5][j] << 16);
        unsigned int w3 = (unsigned int)tileS[cb + 6][j] | ((unsigned int)tileS[cb + 7][j] << 16);
        *(uint4*)((unsigned short*)ftS + ((size_t)b * N_ + pos_s[j]) * C_ + cb) =
            make_uint4(w0, w1, w2, w3);
    }
}

// ---------------- kernel F: per-voxel segmented sum over compacted list ----------------
__global__ void voxel_sum_compact_kernel(const __hip_bfloat16* __restrict__ ftS, // [B,N,C]
                                         const int4* __restrict__ clist,
                                         const int* __restrict__ n_occ,
                                         float* __restrict__ acc) {   // [B,R3,C]
    const int lane = threadIdx.x & 63;
    const int gw = blockIdx.x * (blockDim.x >> 6) + (threadIdx.x >> 6);
    const int nw = gridDim.x * (blockDim.x >> 6);
    const int tot = *n_occ;
    const int sub = lane >> 4;
    const int g   = lane & 15;
    for (int e = gw; e < tot; e += nw) {
        const int4 ent = clist[e];           // wave-uniform broadcast
        const int wid = ent.x, start = ent.y, cnt = ent.z;
        const int b = wid >> 15;             // R3 = 2^15
        const unsigned short* base =
            (const unsigned short*)ftS + ((size_t)b * N_ + start) * C_ + g * 4;
        float a0 = 0.f, a1 = 0.f, a2 = 0.f, a3 = 0.f;
        #pragma unroll 2
        for (int t = sub; t < cnt; t += 4) {
            const ushort4 u = *(const ushort4*)(base + (size_t)t * C_);
            a0 += bf2f(u.x); a1 += bf2f(u.y); a2 += bf2f(u.z); a3 += bf2f(u.w);
        }
        #pragma unroll
        for (int off = 16; off <= 32; off <<= 1) {
            a0 += __shfl_xor(a0, off, 64);
            a1 += __shfl_xor(a1, off, 64);
            a2 += __shfl_xor(a2, off, 64);
            a3 += __shfl_xor(a3, off, 64);
        }
        if (sub == 0) {
            *(float4*)(acc + (size_t)wid * C_ + g * 4) = make_float4(a0, a1, a2, a3);
        }
    }
}

// ---------------- kernel G: transpose acc[b][v][c]/max(cnt,1) -> out[b][c][v] ----------------
__global__ void transpose_finalize_kernel(const float* __restrict__ acc,
                                          const int* __restrict__ counts,
                                          float* __restrict__ out) {
    const int chunk = blockIdx.x;                 // [0, B * R3/64)
    const int b  = chunk >> 9;                    // R3/64 = 512 per batch
    const int v0 = (chunk & 511) * 64;
    __shared__ float tile[64][65];
    __shared__ float cnt_s[64];
    __shared__ int   occ[64];
    const int lane = threadIdx.x & 63, row0 = threadIdx.x >> 6;
    if (threadIdx.x < 64) {
        const int c = counts[b * R3 + v0 + threadIdx.x];
        occ[threadIdx.x]   = c;
        cnt_s[threadIdx.x] = fmaxf((float)c, 1.0f);
    }
    __syncthreads();
    #pragma unroll
    for (int it = 0; it < 16; ++it) {
        const int vi = row0 + it * 4;             // wave-uniform row
        tile[vi][lane] = occ[vi] ? acc[((size_t)(b * R3 + v0 + vi)) * C_ + lane] : 0.f;
    }
    __syncthreads();
    #pragma unroll
    for (int it = 0; it < 16; ++it) {
        const int c = row0 + it * 4;
        out[((size_t)b * C_ + c) * R3 + v0 + lane] = tile[lane][c] / cnt_s[lane];
    }
}

// ============ FALLBACK PATH (round-1 style) ============
__global__ void mean_kernel(const float* __restrict__ coords,
                            float* __restrict__ mean_out) {
    const int ba = blockIdx.x;
    const float* p = coords + (size_t)ba * N_;
    float s = 0.f;
    for (int i = threadIdx.x; i < N_; i += blockDim.x) s += p[i];
    #pragma unroll
    for (int off = 32; off >= 1; off >>= 1) s += __shfl_down(s, off, 64);
    __shared__ float sm[4];
    if ((threadIdx.x & 63) == 0) sm[threadIdx.x >> 6] = s;
    __syncthreads();
    if (threadIdx.x == 0) mean_out[ba] = (sm[0] + sm[1] + sm[2] + sm[3]) / (float)N_;
}

__global__ void maxnorm_kernel(const float* __restrict__ coords,
                               const float* __restrict__ mean,
                               float* __restrict__ maxn) {
    const int b = blockIdx.x;
    const float* p = coords + (size_t)b * 3 * N_;
    const float mx = mean[b * 3 + 0], my = mean[b * 3 + 1], mz = mean[b * 3 + 2];
    float m = 0.f;
    for (int i = threadIdx.x; i < N_; i += blockDim.x) {
        const float x = p[i] - mx, y = p[N_ + i] - my, z = p[2 * N_ + i] - mz;
        m = fmaxf(m, x * x + y * y + z * z);
    }
    #pragma unroll
    for (int off = 32; off >= 1; off >>= 1) m = fmaxf(m, __shfl_down(m, off, 64));
    __shared__ float sm[16];
    if ((threadIdx.x & 63) == 0) sm[threadIdx.x >> 6] = m;
    __syncthreads();
    if (threadIdx.x == 0) {
        float t = sm[0];
        const int nw = blockDim.x >> 6;
        for (int w = 1; w < nw; ++w) t = fmaxf(t, sm[w]);
        maxn[b] = sqrtf(t);
    }
}

__global__ void scatter_kernel(const float* __restrict__ coords,
                               const float* __restrict__ features,
                               const float* __restrict__ mean,
                               const float* __restrict__ maxn,
                               float* __restrict__ out,
                               float* __restrict__ nc_out,
                               float* __restrict__ counts) {
    const int idx = blockIdx.x * blockDim.x + threadIdx.x;
    if (idx >= B_ * N_) return;
    const int b = idx >> 16;
    const int n = idx & (N_ - 1);
    const float* pc = coords + (size_t)b * 3 * N_;
    const float denom = 2.0f * maxn[b];
    int flat = 0;
    #pragma unroll
    for (int a = 0; a < 3; ++a) {
        float v = (pc[(size_t)a * N_ + n] - mean[b * 3 + a]) / denom + 0.5f;
        v = v * (float)Rr;
        v = fminf(fmaxf(v, 0.0f), (float)(Rr - 1));
        nc_out[(size_t)b * 3 * N_ + (size_t)a * N_ + n] = v;
        flat = flat * Rr + (int)rintf(v);
    }
    atomicAdd(&counts[b * R3 + flat], 1.0f);
    const float* pf = features + (size_t)b * C_ * N_ + n;
    float* po = out + (size_t)b * C_ * R3 + flat;
    #pragma unroll 4
    for (int c = 0; c < C_; ++c) atomicAdd(po + (size_t)c * R3, pf[(size_t)c * N_]);
}

__global__ void finalize_kernel(float* __restrict__ out,
                                const float* __restrict__ counts) {
    const int idx = blockIdx.x * blockDim.x + threadIdx.x;
    if (idx >= B_ * C_ * R3) return;
    const int b = idx / (C_ * R3);
    const int v = idx & (R3 - 1);
    out[idx] = out[idx] / fmaxf(counts[b * R3 + v], 1.0f);
}

extern "C" void kernel_launch(void* const* d_in, const int* in_sizes, int n_in,
                              void* d_out, int out_size, void* d_ws, size_t ws_size,
                              hipStream_t stream) {
    const float* features = (const float*)d_in[0];   // [B,C,N]
    const float* coords   = (const float*)d_in[1];   // [B,3,N]

    float* out    = (float*)d_out;                   // [B,C,R,R,R]
    float* nc_out = out + (size_t)B_ * C_ * R3;      // [B,3,N]

    const size_t accB   = (size_t)B_ * R3 * C_ * sizeof(float);  // 64 MiB
    const size_t cntB   = (size_t)B_ * R3 * sizeof(int);         // 1 MiB
    const size_t curB   = cntB;
    const size_t flatB  = (size_t)B_ * N_ * sizeof(int);         // 2 MiB
    const size_t clistB = (size_t)B_ * R3 * sizeof(int4);        // 4 MiB (worst case)
    const size_t smallB = 16384;                                 // n_occ + pmean + pmax
    const size_t ftsB   = (size_t)B_ * N_ * C_ * sizeof(__hip_bfloat16);  // 64 MiB

    const size_t need = accB + cntB + curB + flatB + clistB + smallB + ftsB;
    const int pts = B_ * N_;

    if (ws_size >= need) {
        // -------- sorted-gather fast path (bf16 scratch, per-voxel wave sums) --------
        char* w = (char*)d_ws;
        float* acc    = (float*)w;                 w += accB;    // [B,R3,C] (no memset)
        int*   counts = (int*)w;                   w += cntB;    // [B,R3]
        int*   cursor = (int*)w;                   w += curB;
        int*   flat   = (int*)w;                   w += flatB;   // [B,N]
        int4*  clist  = (int4*)w;                  w += clistB;
        int*   n_occ  = (int*)w;
        float* pmean  = (float*)(w + 16);          // [B*3*PBLK]
        float* pmax   = pmean + B_ * 3 * PBLK;     // [B*PBLKM]
        w += smallB;
        __hip_bfloat16* ftS = (__hip_bfloat16*)w;  // [B,N,C]

        pmean_zero_kernel<<<B_ * 3 * PBLK + 256, 256, 0, stream>>>(
            coords, pmean, (int4*)counts, n_occ);
        partial_max_kernel<<<B_ * PBLKM, 256, 0, stream>>>(coords, pmean, pmax);
        voxelize_kernel<<<pts / 256, 256, 0, stream>>>(
            coords, pmean, pmax, nc_out, flat, counts);
        scan_compact_kernel<<<B_, 1024, 0, stream>>>(counts, cursor, clist, n_occ);
        sorted_transpose_ids_kernel<<<B_ * (N_ / 64), 256, 0, stream>>>(
            features, flat, cursor, ftS);
        voxel_sum_compact_kernel<<<2048, 256, 0, stream>>>(ftS, clist, n_occ, acc);
        transpose_finalize_kernel<<<B_ * (R3 / 64), 256, 0, stream>>>(acc, counts, out);
    } else {
        // -------- fallback path --------
        float* counts = (float*)d_ws;
        float* mean   = counts + (size_t)B_ * R3;
        float* maxn   = mean + B_ * 3;

        hipMemsetAsync(d_out, 0, (size_t)B_ * C_ * R3 * sizeof(float), stream);
        hipMemsetAsync(d_ws, 0, ((size_t)B_ * R3 + B_ * 3 + B_) * sizeof(float), stream);

        mean_kernel<<<B_ * 3, 256, 0, stream>>>(coords, mean);
        maxnorm_kernel<<<B_, 1024, 0, stream>>>(coords, mean, maxn);
        scatter_kernel<<<(pts + 255) / 256, 256, 0, stream>>>(
            coords, features, mean, maxn, out, nc_out, counts);
        finalize_kernel<<<(B_ * C_ * R3 + 255) / 256, 256, 0, stream>>>(out, counts);
    }
}

// Round 16
// 160.616 us; speedup vs baseline: 1.4543x; 1.0323x over previous
//
#include <hip/hip_runtime.h>
#include <hip/hip_bf16.h>
#include <hip/hip_fp8.h>
#include <cstdint>

static constexpr int B_  = 8;
static constexpr int C_  = 64;
static constexpr int N_  = 65536;
static constexpr int Rr  = 32;
static constexpr int R3  = Rr * Rr * Rr;        // 32768 = 2^15
static constexpr int PBLK  = 16;                // partial blocks per (b,axis) for mean
static constexpr int PBLKM = 64;                // partial blocks per batch for max
static constexpr int PTS_PER_BLK  = N_ / PBLK;  // 4096
static constexpr int PTS_PER_BLKM = N_ / PBLKM; // 1024

typedef float f32x4 __attribute__((ext_vector_type(4)));   // native vector: OK for NT builtins

// ---------------- fp8 e4m3 (OCP) via HIP types -> native v_cvt on gfx950 ----------------
__device__ __forceinline__ unsigned int pack4_fp8(float a, float b, float c, float d) {
    __hip_fp8x4_e4m3 q(make_float4(a, b, c, d));
    return *reinterpret_cast<unsigned int*>(&q);
}
__device__ __forceinline__ float4 unpack4_fp8(unsigned int u) {
    __hip_fp8x4_e4m3 q;
    *reinterpret_cast<unsigned int*>(&q) = u;
    return (float4)q;
}

// ---------------- kernel A: partial mean (blocks 0..383) + zero counts/n_occ ----------------
__global__ void pmean_zero_kernel(const float* __restrict__ coords,
                                  float* __restrict__ pmean,
                                  int4* __restrict__ counts4,   // B*R3 ints = 65536 int4
                                  int* __restrict__ n_occ) {
    if (blockIdx.x >= B_ * 3 * PBLK) {
        const int zb = blockIdx.x - B_ * 3 * PBLK;     // 0..255
        counts4[zb * 256 + threadIdx.x] = make_int4(0, 0, 0, 0);
        if (zb == 0 && threadIdx.x == 0) *n_occ = 0;
        return;
    }
    const int blk = blockIdx.x & (PBLK - 1);
    const int ba  = blockIdx.x / PBLK;
    const float4* p = (const float4*)(coords + (size_t)ba * N_ + (size_t)blk * PTS_PER_BLK);
    float s = 0.f;
    #pragma unroll
    for (int k = 0; k < PTS_PER_BLK / 4 / 256; ++k) {   // 4 iters
        float4 v = p[k * 256 + threadIdx.x];
        s += (v.x + v.y) + (v.z + v.w);
    }
    #pragma unroll
    for (int off = 32; off >= 1; off >>= 1) s += __shfl_down(s, off, 64);
    __shared__ float sm[4];
    if ((threadIdx.x & 63) == 0) sm[threadIdx.x >> 6] = s;
    __syncthreads();
    if (threadIdx.x == 0) pmean[blockIdx.x] = sm[0] + sm[1] + sm[2] + sm[3];
}

// ---------------- kernel B: partial max of centered norm^2 (512 blocks) ----------------
__global__ void partial_max_kernel(const float* __restrict__ coords,
                                   const float* __restrict__ pmean,
                                   float* __restrict__ pmax) {
    const int blk = blockIdx.x & (PBLKM - 1);
    const int b   = blockIdx.x / PBLKM;
    __shared__ float msh[3];
    if (threadIdx.x == 0) {
        #pragma unroll
        for (int a = 0; a < 3; ++a) {
            float t = 0.f;
            #pragma unroll
            for (int k = 0; k < PBLK; ++k) t += pmean[(b * 3 + a) * PBLK + k];
            msh[a] = t / (float)N_;
        }
    }
    __syncthreads();
    const float mx = msh[0], my = msh[1], mz = msh[2];
    const float4* px = (const float4*)(coords + (size_t)b * 3 * N_ + (size_t)blk * PTS_PER_BLKM);
    const float4* py = px + N_ / 4;
    const float4* pz = px + 2 * (N_ / 4);
    const int i = threadIdx.x;           // exactly one float4 per thread
    float4 x = px[i], y = py[i], z = pz[i];
    float m = 0.f;
    {
        float x0 = x.x - mx, y0 = y.x - my, z0 = z.x - mz;
        float x1 = x.y - mx, y1 = y.y - my, z1 = z.y - mz;
        float x2 = x.z - mx, y2 = y.z - my, z2 = z.z - mz;
        float x3 = x.w - mx, y3 = y.w - my, z3 = z.w - mz;
        m = fmaxf(m, x0 * x0 + y0 * y0 + z0 * z0);
        m = fmaxf(m, x1 * x1 + y1 * y1 + z1 * z1);
        m = fmaxf(m, x2 * x2 + y2 * y2 + z2 * z2);
        m = fmaxf(m, x3 * x3 + y3 * y3 + z3 * z3);
    }
    #pragma unroll
    for (int off = 32; off >= 1; off >>= 1) m = fmaxf(m, __shfl_down(m, off, 64));
    __shared__ float sm[4];
    if ((threadIdx.x & 63) == 0) sm[threadIdx.x >> 6] = m;
    __syncthreads();
    if (threadIdx.x == 0)
        pmax[blockIdx.x] = fmaxf(fmaxf(sm[0], sm[1]), fmaxf(sm[2], sm[3]));
}

// ---------------- kernel C: voxelize: nc_out + flat ids + int counts ----------------
__global__ void voxelize_kernel(const float* __restrict__ coords,
                                const float* __restrict__ pmean,
                                const float* __restrict__ pmax,
                                float* __restrict__ nc_out,     // [B,3,N]
                                int* __restrict__ flat_out,     // [B,N]
                                int* __restrict__ counts) {     // [B,R3], pre-zeroed
    const int idx = blockIdx.x * blockDim.x + threadIdx.x;
    const int b = idx >> 16;            // block spans one b (256 | N)
    const int n = idx & (N_ - 1);
    __shared__ float par[4];            // mx,my,mz,denom
    if (threadIdx.x == 0) {
        #pragma unroll
        for (int a = 0; a < 3; ++a) {
            float t = 0.f;
            #pragma unroll
            for (int k = 0; k < PBLK; ++k) t += pmean[(b * 3 + a) * PBLK + k];
            par[a] = t / (float)N_;
        }
        float mm = 0.f;
        #pragma unroll
        for (int k = 0; k < PBLKM; ++k) mm = fmaxf(mm, pmax[b * PBLKM + k]);
        par[3] = 2.0f * sqrtf(mm);      // EPS == 0; sqrt(max n2) == max norm
    }
    __syncthreads();
    const float* pc = coords + (size_t)b * 3 * N_;
    const float denom = par[3];
    int flat = 0;
    #pragma unroll
    for (int a = 0; a < 3; ++a) {
        float v = (pc[(size_t)a * N_ + n] - par[a]) / denom + 0.5f;
        v = v * (float)Rr;
        v = fminf(fmaxf(v, 0.0f), (float)(Rr - 1));
        nc_out[(size_t)b * 3 * N_ + (size_t)a * N_ + n] = v;
        flat = flat * Rr + (int)rintf(v);   // round half to even == jnp.round
    }
    flat_out[idx] = flat;
    atomicAdd(&counts[b * R3 + flat], 1);
}

// ---------------- kernel D: per-batch scan + compaction, shfl-based (2 barriers) ----------------
__global__ void scan_compact_kernel(const int* __restrict__ counts,
                                    int* __restrict__ cursor,
                                    int4* __restrict__ clist,
                                    int* __restrict__ n_occ) {
    const int b = blockIdx.x;          // [0,B)
    const int t = threadIdx.x;         // 1024 threads
    const int lane = t & 63, wv = t >> 6;    // 16 waves
    constexpr int PER = R3 / 1024;     // 32
    int local[PER];
    const int4* c4 = (const int4*)(counts + b * R3);
    int s = 0, nz = 0;
    #pragma unroll
    for (int k = 0; k < PER / 4; ++k) {      // 8 int4 loads
        const int4 v = c4[t * (PER / 4) + k];
        local[k * 4 + 0] = v.x; local[k * 4 + 1] = v.y;
        local[k * 4 + 2] = v.z; local[k * 4 + 3] = v.w;
        s  += v.x + v.y + v.z + v.w;
        nz += (v.x > 0) + (v.y > 0) + (v.z > 0) + (v.w > 0);
    }
    const int s_own = s, nz_own = nz;
    #pragma unroll
    for (int off = 1; off < 64; off <<= 1) {
        const int vs = __shfl_up(s, off, 64);
        const int vn = __shfl_up(nz, off, 64);
        if (lane >= off) { s += vs; nz += vn; }
    }
    __shared__ int wsum[16], wnz[16], woffs[16], woffn[16];
    __shared__ int basesh;
    if (lane == 63) { wsum[wv] = s; wnz[wv] = nz; }
    __syncthreads();
    if (t < 16) {
        const int as = wsum[t], an = wnz[t];
        int is = as, in_ = an;
        #pragma unroll
        for (int off = 1; off < 16; off <<= 1) {
            const int vs = __shfl_up(is, off, 16);
            const int vn = __shfl_up(in_, off, 16);
            if (t >= off) { is += vs; in_ += vn; }
        }
        woffs[t] = is - as;
        woffn[t] = in_ - an;
        if (t == 15) basesh = atomicAdd(n_occ, in_);
    }
    __syncthreads();
    int run  = woffs[wv] + (s - s_own);
    int slot = basesh + woffn[wv] + (nz - nz_own);
    int* cur = cursor + b * R3 + t * PER;
    #pragma unroll
    for (int k = 0; k < PER; ++k) {
        cur[k] = run;
        if (local[k] > 0) clist[slot++] = make_int4(b * R3 + t * PER + k, run, local[k], 0);
        run += local[k];
    }
}

// ---------------- kernel E: fused pos-assign + transpose into sorted order (fp8, HW cvt) ----------------
// features loads NON-TEMPORAL; ftS row = 64 B fp8 -> halved scattered writes.
__global__ void sorted_transpose_ids_kernel(const float* __restrict__ features,
                                            const int* __restrict__ flat,
                                            int* __restrict__ cursor,
                                            unsigned char* __restrict__ ftS) {
    const int tile = blockIdx.x & 1023;   // N/64 tiles per batch
    const int b    = blockIdx.x >> 10;
    const int n0   = tile * 64;
    __shared__ unsigned char tileS[64][68];    // [channel][point], pitch 68 (4B-aligned rows)
    __shared__ int pos_s[64];
    const int t = threadIdx.x;
    if (t < 64) {
        const int f = flat[b * N_ + n0 + t];
        pos_s[t] = atomicAdd(&cursor[b * R3 + f], 1);
    }
    const int g  = t & 15;           // 16 float4 lanes per channel row
    const int c0 = t >> 4;           // 0..15
    #pragma unroll
    for (int it = 0; it < 4; ++it) {
        const int c = it * 16 + c0;
        const f32x4 v = __builtin_nontemporal_load(
            (const f32x4*)(features + ((size_t)b * C_ + c) * N_ + n0 + g * 4));
        const unsigned int u = pack4_fp8(v.x, v.y, v.z, v.w);   // 2 HW cvt instrs
        *(unsigned int*)&tileS[c][g * 4] = u;   // addr = c*68 + g*4, 4B aligned
    }
    __syncthreads();
    // store: thread -> (point row j = t>>2, 16B quad q = t&3); row = 64 B contiguous in ftS
    const int j = t >> 2, q = t & 3, cb = q * 16;
    unsigned int w0 = (unsigned int)tileS[cb + 0][j] | ((unsigned int)tileS[cb + 1][j] << 8) |
                      ((unsigned int)tileS[cb + 2][j] << 16) | ((unsigned int)tileS[cb + 3][j] << 24);
    unsigned int w1 = (unsigned int)tileS[cb + 4][j] | ((unsigned int)tileS[cb + 5][j] << 8) |
                      ((unsigned int)tileS[cb + 6][j] << 16) | ((unsigned int)tileS[cb + 7][j] << 24);
    unsigned int w2 = (unsigned int)tileS[cb + 8][j] | ((unsigned int)tileS[cb + 9][j] << 8) |
                      ((unsigned int)tileS[cb + 10][j] << 16) | ((unsigned int)tileS[cb + 11][j] << 24);
    unsigned int w3 = (unsigned int)tileS[cb + 12][j] | ((unsigned int)tileS[cb + 13][j] << 8) |
                      ((unsigned int)tileS[cb + 14][j] << 16) | ((unsigned int)tileS[cb + 15][j] << 24);
    *(uint4*)(ftS + ((size_t)b * N_ + pos_s[j]) * C_ + cb) = make_uint4(w0, w1, w2, w3);
}

// ---------------- kernel F: per-voxel segmented sum over compacted list (fp8 in, f32 acc) ----------------
__global__ void voxel_sum_compact_kernel(const unsigned char* __restrict__ ftS, // [B,N,C] fp8
                                         const int4* __restrict__ clist,
                                         const int* __restrict__ n_occ,
                                         float* __restrict__ acc) {   // [B,R3,C]
    const int lane = threadIdx.x & 63;
    const int gw = blockIdx.x * (blockDim.x >> 6) + (threadIdx.x >> 6);
    const int nw = gridDim.x * (blockDim.x >> 6);
    const int tot = *n_occ;
    const int sub = lane >> 4;
    const int g   = lane & 15;
    for (int e = gw; e < tot; e += nw) {
        const int4 ent = clist[e];           // wave-uniform broadcast
        const int wid = ent.x, start = ent.y, cnt = ent.z;
        const int b = wid >> 15;             // R3 = 2^15
        const unsigned char* base = ftS + ((size_t)b * N_ + start) * C_ + g * 4;
        float a0 = 0.f, a1 = 0.f, a2 = 0.f, a3 = 0.f;
        #pragma unroll 2
        for (int t = sub; t < cnt; t += 4) {
            const unsigned int u = *(const unsigned int*)(base + (size_t)t * C_);
            const float4 f = unpack4_fp8(u);         // 2 HW cvt instrs
            a0 += f.x; a1 += f.y; a2 += f.z; a3 += f.w;
        }
        #pragma unroll
        for (int off = 16; off <= 32; off <<= 1) {
            a0 += __shfl_xor(a0, off, 64);
            a1 += __shfl_xor(a1, off, 64);
            a2 += __shfl_xor(a2, off, 64);
            a3 += __shfl_xor(a3, off, 64);
        }
        if (sub == 0) {
            *(float4*)(acc + (size_t)wid * C_ + g * 4) = make_float4(a0, a1, a2, a3);
        }
    }
}

// ---------------- kernel G: transpose acc[b][v][c]/max(cnt,1) -> out[b][c][v] ----------------
__global__ void transpose_finalize_kernel(const float* __restrict__ acc,
                                          const int* __restrict__ counts,
                                          float* __restrict__ out) {
    const int chunk = blockIdx.x;                 // [0, B * R3/64)
    const int b  = chunk >> 9;                    // R3/64 = 512 per batch
    const int v0 = (chunk & 511) * 64;
    __shared__ float tile[64][65];
    __shared__ float cnt_s[64];
    __shared__ int   occ[64];
    const int lane = threadIdx.x & 63, row0 = threadIdx.x >> 6;
    if (threadIdx.x < 64) {
        const int c = counts[b * R3 + v0 + threadIdx.x];
        occ[threadIdx.x]   = c;
        cnt_s[threadIdx.x] = fmaxf((float)c, 1.0f);
    }
    __syncthreads();
    #pragma unroll
    for (int it = 0; it < 16; ++it) {
        const int vi = row0 + it * 4;             // wave-uniform row
        tile[vi][lane] = occ[vi] ? acc[((size_t)(b * R3 + v0 + vi)) * C_ + lane] : 0.f;
    }
    __syncthreads();
    #pragma unroll
    for (int it = 0; it < 16; ++it) {
        const int c = row0 + it * 4;
        out[((size_t)b * C_ + c) * R3 + v0 + lane] = tile[lane][c] / cnt_s[lane];
    }
}

// ============ FALLBACK PATH (round-1 style) ============
__global__ void mean_kernel(const float* __restrict__ coords,
                            float* __restrict__ mean_out) {
    const int ba = blockIdx.x;
    const float* p = coords + (size_t)ba * N_;
    float s = 0.f;
    for (int i = threadIdx.x; i < N_; i += blockDim.x) s += p[i];
    #pragma unroll
    for (int off = 32; off >= 1; off >>= 1) s += __shfl_down(s, off, 64);
    __shared__ float sm[4];
    if ((threadIdx.x & 63) == 0) sm[threadIdx.x >> 6] = s;
    __syncthreads();
    if (threadIdx.x == 0) mean_out[ba] = (sm[0] + sm[1] + sm[2] + sm[3]) / (float)N_;
}

__global__ void maxnorm_kernel(const float* __restrict__ coords,
                               const float* __restrict__ mean,
                               float* __restrict__ maxn) {
    const int b = blockIdx.x;
    const float* p = coords + (size_t)b * 3 * N_;
    const float mx = mean[b * 3 + 0], my = mean[b * 3 + 1], mz = mean[b * 3 + 2];
    float m = 0.f;
    for (int i = threadIdx.x; i < N_; i += blockDim.x) {
        const float x = p[i] - mx, y = p[N_ + i] - my, z = p[2 * N_ + i] - mz;
        m = fmaxf(m, x * x + y * y + z * z);
    }
    #pragma unroll
    for (int off = 32; off >= 1; off >>= 1) m = fmaxf(m, __shfl_down(m, off, 64));
    __shared__ float sm[16];
    if ((threadIdx.x & 63) == 0) sm[threadIdx.x >> 6] = m;
    __syncthreads();
    if (threadIdx.x == 0) {
        float t = sm[0];
        const int nw = blockDim.x >> 6;
        for (int w = 1; w < nw; ++w) t = fmaxf(t, sm[w]);
        maxn[b] = sqrtf(t);
    }
}

__global__ void scatter_kernel(const float* __restrict__ coords,
                               const float* __restrict__ features,
                               const float* __restrict__ mean,
                               const float* __restrict__ maxn,
                               float* __restrict__ out,
                               float* __restrict__ nc_out,
                               float* __restrict__ counts) {
    const int idx = blockIdx.x * blockDim.x + threadIdx.x;
    if (idx >= B_ * N_) return;
    const int b = idx >> 16;
    const int n = idx & (N_ - 1);
    const float* pc = coords + (size_t)b * 3 * N_;
    const float denom = 2.0f * maxn[b];
    int flat = 0;
    #pragma unroll
    for (int a = 0; a < 3; ++a) {
        float v = (pc[(size_t)a * N_ + n] - mean[b * 3 + a]) / denom + 0.5f;
        v = v * (float)Rr;
        v = fminf(fmaxf(v, 0.0f), (float)(Rr - 1));
        nc_out[(size_t)b * 3 * N_ + (size_t)a * N_ + n] = v;
        flat = flat * Rr + (int)rintf(v);
    }
    atomicAdd(&counts[b * R3 + flat], 1.0f);
    const float* pf = features + (size_t)b * C_ * N_ + n;
    float* po = out + (size_t)b * C_ * R3 + flat;
    #pragma unroll 4
    for (int c = 0; c < C_; ++c) atomicAdd(po + (size_t)c * R3, pf[(size_t)c * N_]);
}

__global__ void finalize_kernel(float* __restrict__ out,
                                const float* __restrict__ counts) {
    const int idx = blockIdx.x * blockDim.x + threadIdx.x;
    if (idx >= B_ * C_ * R3) return;
    const int b = idx / (C_ * R3);
    const int v = idx & (R3 - 1);
    out[idx] = out[idx] / fmaxf(counts[b * R3 + v], 1.0f);
}

extern "C" void kernel_launch(void* const* d_in, const int* in_sizes, int n_in,
                              void* d_out, int out_size, void* d_ws, size_t ws_size,
                              hipStream_t stream) {
    const float* features = (const float*)d_in[0];   // [B,C,N]
    const float* coords   = (const float*)d_in[1];   // [B,3,N]

    float* out    = (float*)d_out;                   // [B,C,R,R,R]
    float* nc_out = out + (size_t)B_ * C_ * R3;      // [B,3,N]

    const size_t accB   = (size_t)B_ * R3 * C_ * sizeof(float);  // 64 MiB
    const size_t cntB   = (size_t)B_ * R3 * sizeof(int);         // 1 MiB
    const size_t curB   = cntB;
    const size_t flatB  = (size_t)B_ * N_ * sizeof(int);         // 2 MiB
    const size_t clistB = (size_t)B_ * R3 * sizeof(int4);        // 4 MiB (worst case)
    const size_t smallB = 16384;                                 // n_occ + pmean + pmax
    const size_t ftsB   = (size_t)B_ * N_ * C_;                  // 32 MiB (fp8)

    const size_t need = accB + cntB + curB + flatB + clistB + smallB + ftsB;
    const int pts = B_ * N_;

    if (ws_size >= need) {
        // -------- sorted-gather fast path (fp8 scratch w/ HW cvt, per-voxel wave sums) --------
        char* w = (char*)d_ws;
        float* acc    = (float*)w;                 w += accB;    // [B,R3,C] (no memset)
        int*   counts = (int*)w;                   w += cntB;    // [B,R3]
        int*   cursor = (int*)w;                   w += curB;
        int*   flat   = (int*)w;                   w += flatB;   // [B,N]
        int4*  clist  = (int4*)w;                  w += clistB;
        int*   n_occ  = (int*)w;
        float* pmean  = (float*)(w + 16);          // [B*3*PBLK]
        float* pmax   = pmean + B_ * 3 * PBLK;     // [B*PBLKM]
        w += smallB;
        unsigned char* ftS = (unsigned char*)w;    // [B,N,C] fp8

        pmean_zero_kernel<<<B_ * 3 * PBLK + 256, 256, 0, stream>>>(
            coords, pmean, (int4*)counts, n_occ);
        partial_max_kernel<<<B_ * PBLKM, 256, 0, stream>>>(coords, pmean, pmax);
        voxelize_kernel<<<pts / 256, 256, 0, stream>>>(
            coords, pmean, pmax, nc_out, flat, counts);
        scan_compact_kernel<<<B_, 1024, 0, stream>>>(counts, cursor, clist, n_occ);
        sorted_transpose_ids_kernel<<<B_ * (N_ / 64), 256, 0, stream>>>(
            features, flat, cursor, ftS);
        voxel_sum_compact_kernel<<<2048, 256, 0, stream>>>(ftS, clist, n_occ, acc);
        transpose_finalize_kernel<<<B_ * (R3 / 64), 256, 0, stream>>>(acc, counts, out);
    } else {
        // -------- fallback path --------
        float* counts = (float*)d_ws;
        float* mean   = counts + (size_t)B_ * R3;
        float* maxn   = mean + B_ * 3;

        hipMemsetAsync(d_out, 0, (size_t)B_ * C_ * R3 * sizeof(float), stream);
        hipMemsetAsync(d_ws, 0, ((size_t)B_ * R3 + B_ * 3 + B_) * sizeof(float), stream);

        mean_kernel<<<B_ * 3, 256, 0, stream>>>(coords, mean);
        maxnorm_kernel<<<B_, 1024, 0, stream>>>(coords, mean, maxn);
        scatter_kernel<<<(pts + 255) / 256, 256, 0, stream>>>(
            coords, features, mean, maxn, out, nc_out, counts);
        finalize_kernel<<<(B_ * C_ * R3 + 255) / 256, 256, 0, stream>>>(out, counts);
    }
}

// Round 17
// 159.248 us; speedup vs baseline: 1.4668x; 1.0086x over previous
//
#include <hip/hip_runtime.h>
#include <hip/hip_bf16.h>
#include <hip/hip_fp8.h>
#include <cstdint>

static constexpr int B_  = 8;
static constexpr int C_  = 64;
static constexpr int N_  = 65536;
static constexpr int Rr  = 32;
static constexpr int R3  = Rr * Rr * Rr;        // 32768 = 2^15
static constexpr int PBLK  = 16;
static constexpr int PBLKM = 64;
static constexpr int PTS_PER_BLK  = N_ / PBLK;  // 4096
static constexpr int PTS_PER_BLKM = N_ / PBLKM; // 1024

typedef float f32x4 __attribute__((ext_vector_type(4)));

__device__ __forceinline__ unsigned int pack4_fp8(float a, float b, float c, float d) {
    __hip_fp8x4_e4m3 q(make_float4(a, b, c, d));
    return *reinterpret_cast<unsigned int*>(&q);
}
__device__ __forceinline__ float4 unpack4_fp8(unsigned int u) {
    __hip_fp8x4_e4m3 q;
    *reinterpret_cast<unsigned int*>(&q) = u;
    return (float4)q;
}

// ---------------- kernel A: partial mean + zero counts/n_occ ----------------
__global__ void pmean_zero_kernel(const float* __restrict__ coords,
                                  float* __restrict__ pmean,
                                  int4* __restrict__ counts4,
                                  int* __restrict__ n_occ) {
    if (blockIdx.x >= B_ * 3 * PBLK) {
        const int zb = blockIdx.x - B_ * 3 * PBLK;
        counts4[zb * 256 + threadIdx.x] = make_int4(0, 0, 0, 0);
        if (zb == 0 && threadIdx.x == 0) *n_occ = 0;
        return;
    }
    const int blk = blockIdx.x & (PBLK - 1);
    const int ba  = blockIdx.x / PBLK;
    const float4* p = (const float4*)(coords + (size_t)ba * N_ + (size_t)blk * PTS_PER_BLK);
    float s = 0.f;
    #pragma unroll
    for (int k = 0; k < PTS_PER_BLK / 4 / 256; ++k) {
        float4 v = p[k * 256 + threadIdx.x];
        s += (v.x + v.y) + (v.z + v.w);
    }
    #pragma unroll
    for (int off = 32; off >= 1; off >>= 1) s += __shfl_down(s, off, 64);
    __shared__ float sm[4];
    if ((threadIdx.x & 63) == 0) sm[threadIdx.x >> 6] = s;
    __syncthreads();
    if (threadIdx.x == 0) pmean[blockIdx.x] = sm[0] + sm[1] + sm[2] + sm[3];
}

// ---------------- kernel B: partial max of centered norm^2 ----------------
__global__ void partial_max_kernel(const float* __restrict__ coords,
                                   const float* __restrict__ pmean,
                                   float* __restrict__ pmax) {
    const int blk = blockIdx.x & (PBLKM - 1);
    const int b   = blockIdx.x / PBLKM;
    __shared__ float msh[3];
    if (threadIdx.x == 0) {
        #pragma unroll
        for (int a = 0; a < 3; ++a) {
            float t = 0.f;
            #pragma unroll
            for (int k = 0; k < PBLK; ++k) t += pmean[(b * 3 + a) * PBLK + k];
            msh[a] = t / (float)N_;
        }
    }
    __syncthreads();
    const float mx = msh[0], my = msh[1], mz = msh[2];
    const float4* px = (const float4*)(coords + (size_t)b * 3 * N_ + (size_t)blk * PTS_PER_BLKM);
    const float4* py = px + N_ / 4;
    const float4* pz = px + 2 * (N_ / 4);
    const int i = threadIdx.x;
    float4 x = px[i], y = py[i], z = pz[i];
    float m = 0.f;
    {
        float x0 = x.x - mx, y0 = y.x - my, z0 = z.x - mz;
        float x1 = x.y - mx, y1 = y.y - my, z1 = z.y - mz;
        float x2 = x.z - mx, y2 = y.z - my, z2 = z.z - mz;
        float x3 = x.w - mx, y3 = y.w - my, z3 = z.w - mz;
        m = fmaxf(m, x0 * x0 + y0 * y0 + z0 * z0);
        m = fmaxf(m, x1 * x1 + y1 * y1 + z1 * z1);
        m = fmaxf(m, x2 * x2 + y2 * y2 + z2 * z2);
        m = fmaxf(m, x3 * x3 + y3 * y3 + z3 * z3);
    }
    #pragma unroll
    for (int off = 32; off >= 1; off >>= 1) m = fmaxf(m, __shfl_down(m, off, 64));
    __shared__ float sm[4];
    if ((threadIdx.x & 63) == 0) sm[threadIdx.x >> 6] = m;
    __syncthreads();
    if (threadIdx.x == 0)
        pmax[blockIdx.x] = fmaxf(fmaxf(sm[0], sm[1]), fmaxf(sm[2], sm[3]));
}

// ---------------- kernel C: voxelize ----------------
__global__ void voxelize_kernel(const float* __restrict__ coords,
                                const float* __restrict__ pmean,
                                const float* __restrict__ pmax,
                                float* __restrict__ nc_out,
                                int* __restrict__ flat_out,
                                int* __restrict__ counts) {
    const int idx = blockIdx.x * blockDim.x + threadIdx.x;
    const int b = idx >> 16;
    const int n = idx & (N_ - 1);
    __shared__ float par[4];
    if (threadIdx.x == 0) {
        #pragma unroll
        for (int a = 0; a < 3; ++a) {
            float t = 0.f;
            #pragma unroll
            for (int k = 0; k < PBLK; ++k) t += pmean[(b * 3 + a) * PBLK + k];
            par[a] = t / (float)N_;
        }
        float mm = 0.f;
        #pragma unroll
        for (int k = 0; k < PBLKM; ++k) mm = fmaxf(mm, pmax[b * PBLKM + k]);
        par[3] = 2.0f * sqrtf(mm);
    }
    __syncthreads();
    const float* pc = coords + (size_t)b * 3 * N_;
    const float denom = par[3];
    int flat = 0;
    #pragma unroll
    for (int a = 0; a < 3; ++a) {
        float v = (pc[(size_t)a * N_ + n] - par[a]) / denom + 0.5f;
        v = v * (float)Rr;
        v = fminf(fmaxf(v, 0.0f), (float)(Rr - 1));
        nc_out[(size_t)b * 3 * N_ + (size_t)a * N_ + n] = v;
        flat = flat * Rr + (int)rintf(v);
    }
    flat_out[idx] = flat;
    atomicAdd(&counts[b * R3 + flat], 1);
}

// ---------------- kernel D: per-batch scan + compaction ----------------
__global__ void scan_compact_kernel(const int* __restrict__ counts,
                                    int* __restrict__ cursor,
                                    int4* __restrict__ clist,
                                    int* __restrict__ n_occ) {
    const int b = blockIdx.x;
    const int t = threadIdx.x;
    const int lane = t & 63, wv = t >> 6;
    constexpr int PER = R3 / 1024;
    int local[PER];
    const int4* c4 = (const int4*)(counts + b * R3);
    int s = 0, nz = 0;
    #pragma unroll
    for (int k = 0; k < PER / 4; ++k) {
        const int4 v = c4[t * (PER / 4) + k];
        local[k * 4 + 0] = v.x; local[k * 4 + 1] = v.y;
        local[k * 4 + 2] = v.z; local[k * 4 + 3] = v.w;
        s  += v.x + v.y + v.z + v.w;
        nz += (v.x > 0) + (v.y > 0) + (v.z > 0) + (v.w > 0);
    }
    const int s_own = s, nz_own = nz;
    #pragma unroll
    for (int off = 1; off < 64; off <<= 1) {
        const int vs = __shfl_up(s, off, 64);
        const int vn = __shfl_up(nz, off, 64);
        if (lane >= off) { s += vs; nz += vn; }
    }
    __shared__ int wsum[16], wnz[16], woffs[16], woffn[16];
    __shared__ int basesh;
    if (lane == 63) { wsum[wv] = s; wnz[wv] = nz; }
    __syncthreads();
    if (t < 16) {
        const int as = wsum[t], an = wnz[t];
        int is = as, in_ = an;
        #pragma unroll
        for (int off = 1; off < 16; off <<= 1) {
            const int vs = __shfl_up(is, off, 16);
            const int vn = __shfl_up(in_, off, 16);
            if (t >= off) { is += vs; in_ += vn; }
        }
        woffs[t] = is - as;
        woffn[t] = in_ - an;
        if (t == 15) basesh = atomicAdd(n_occ, in_);
    }
    __syncthreads();
    int run  = woffs[wv] + (s - s_own);
    int slot = basesh + woffn[wv] + (nz - nz_own);
    int* cur = cursor + b * R3 + t * PER;
    #pragma unroll
    for (int k = 0; k < PER; ++k) {
        cur[k] = run;
        if (local[k] > 0) clist[slot++] = make_int4(b * R3 + t * PER + k, run, local[k], 0);
        run += local[k];
    }
}

// ---------------- kernel E: fused pos-assign + fp8 transpose (NT loads, HW cvt) ----------------
__global__ void sorted_transpose_ids_kernel(const float* __restrict__ features,
                                            const int* __restrict__ flat,
                                            int* __restrict__ cursor,
                                            unsigned char* __restrict__ ftS) {
    const int tile = blockIdx.x & 1023;
    const int b    = blockIdx.x >> 10;
    const int n0   = tile * 64;
    __shared__ unsigned char tileS[64][68];
    __shared__ int pos_s[64];
    const int t = threadIdx.x;
    if (t < 64) {
        const int f = flat[b * N_ + n0 + t];
        pos_s[t] = atomicAdd(&cursor[b * R3 + f], 1);
    }
    const int g  = t & 15;
    const int c0 = t >> 4;
    #pragma unroll
    for (int it = 0; it < 4; ++it) {
        const int c = it * 16 + c0;
        const f32x4 v = __builtin_nontemporal_load(
            (const f32x4*)(features + ((size_t)b * C_ + c) * N_ + n0 + g * 4));
        *(unsigned int*)&tileS[c][g * 4] = pack4_fp8(v.x, v.y, v.z, v.w);
    }
    __syncthreads();
    const int j = t >> 2, q = t & 3, cb = q * 16;
    unsigned int w0 = (unsigned int)tileS[cb + 0][j] | ((unsigned int)tileS[cb + 1][j] << 8) |
                      ((unsigned int)tileS[cb + 2][j] << 16) | ((unsigned int)tileS[cb + 3][j] << 24);
    unsigned int w1 = (unsigned int)tileS[cb + 4][j] | ((unsigned int)tileS[cb + 5][j] << 8) |
                      ((unsigned int)tileS[cb + 6][j] << 16) | ((unsigned int)tileS[cb + 7][j] << 24);
    unsigned int w2 = (unsigned int)tileS[cb + 8][j] | ((unsigned int)tileS[cb + 9][j] << 8) |
                      ((unsigned int)tileS[cb + 10][j] << 16) | ((unsigned int)tileS[cb + 11][j] << 24);
    unsigned int w3 = (unsigned int)tileS[cb + 12][j] | ((unsigned int)tileS[cb + 13][j] << 8) |
                      ((unsigned int)tileS[cb + 14][j] << 16) | ((unsigned int)tileS[cb + 15][j] << 24);
    *(uint4*)(ftS + ((size_t)b * N_ + pos_s[j]) * C_ + cb) = make_uint4(w0, w1, w2, w3);
}

// ---------------- kernel F: per-voxel segmented sum ----------------
__global__ void voxel_sum_compact_kernel(const unsigned char* __restrict__ ftS,
                                         const int4* __restrict__ clist,
                                         const int* __restrict__ n_occ,
                                         float* __restrict__ acc) {
    const int lane = threadIdx.x & 63;
    const int gw = blockIdx.x * (blockDim.x >> 6) + (threadIdx.x >> 6);
    const int nw = gridDim.x * (blockDim.x >> 6);
    const int tot = *n_occ;
    const int sub = lane >> 4;
    const int g   = lane & 15;
    for (int e = gw; e < tot; e += nw) {
        const int4 ent = clist[e];
        const int wid = ent.x, start = ent.y, cnt = ent.z;
        const int b = wid >> 15;
        const unsigned char* base = ftS + ((size_t)b * N_ + start) * C_ + g * 4;
        float a0 = 0.f, a1 = 0.f, a2 = 0.f, a3 = 0.f;
        #pragma unroll 2
        for (int t = sub; t < cnt; t += 4) {
            const unsigned int u = *(const unsigned int*)(base + (size_t)t * C_);
            const float4 f = unpack4_fp8(u);
            a0 += f.x; a1 += f.y; a2 += f.z; a3 += f.w;
        }
        #pragma unroll
        for (int off = 16; off <= 32; off <<= 1) {
            a0 += __shfl_xor(a0, off, 64);
            a1 += __shfl_xor(a1, off, 64);
            a2 += __shfl_xor(a2, off, 64);
            a3 += __shfl_xor(a3, off, 64);
        }
        if (sub == 0) {
            *(float4*)(acc + (size_t)wid * C_ + g * 4) = make_float4(a0, a1, a2, a3);
        }
    }
}

// ---------------- kernel G: transpose/divide -> out ----------------
__global__ void transpose_finalize_kernel(const float* __restrict__ acc,
                                          const int* __restrict__ counts,
                                          float* __restrict__ out) {
    const int chunk = blockIdx.x;
    const int b  = chunk >> 9;
    const int v0 = (chunk & 511) * 64;
    __shared__ float tile[64][65];
    __shared__ float cnt_s[64];
    __shared__ int   occ[64];
    const int lane = threadIdx.x & 63, row0 = threadIdx.x >> 6;
    if (threadIdx.x < 64) {
        const int c = counts[b * R3 + v0 + threadIdx.x];
        occ[threadIdx.x]   = c;
        cnt_s[threadIdx.x] = fmaxf((float)c, 1.0f);
    }
    __syncthreads();
    #pragma unroll
    for (int it = 0; it < 16; ++it) {
        const int vi = row0 + it * 4;
        tile[vi][lane] = occ[vi] ? acc[((size_t)(b * R3 + v0 + vi)) * C_ + lane] : 0.f;
    }
    __syncthreads();
    #pragma unroll
    for (int it = 0; it < 16; ++it) {
        const int c = row0 + it * 4;
        out[((size_t)b * C_ + c) * R3 + v0 + lane] = tile[lane][c] / cnt_s[lane];
    }
}

// ============ FALLBACK PATH (round-1 style) ============
__global__ void mean_kernel(const float* __restrict__ coords,
                            float* __restrict__ mean_out) {
    const int ba = blockIdx.x;
    const float* p = coords + (size_t)ba * N_;
    float s = 0.f;
    for (int i = threadIdx.x; i < N_; i += blockDim.x) s += p[i];
    #pragma unroll
    for (int off = 32; off >= 1; off >>= 1) s += __shfl_down(s, off, 64);
    __shared__ float sm[4];
    if ((threadIdx.x & 63) == 0) sm[threadIdx.x >> 6] = s;
    __syncthreads();
    if (threadIdx.x == 0) mean_out[ba] = (sm[0] + sm[1] + sm[2] + sm[3]) / (float)N_;
}

__global__ void maxnorm_kernel(const float* __restrict__ coords,
                               const float* __restrict__ mean,
                               float* __restrict__ maxn) {
    const int b = blockIdx.x;
    const float* p = coords + (size_t)b * 3 * N_;
    const float mx = mean[b * 3 + 0], my = mean[b * 3 + 1], mz = mean[b * 3 + 2];
    float m = 0.f;
    for (int i = threadIdx.x; i < N_; i += blockDim.x) {
        const float x = p[i] - mx, y = p[N_ + i] - my, z = p[2 * N_ + i] - mz;
        m = fmaxf(m, x * x + y * y + z * z);
    }
    #pragma unroll
    for (int off = 32; off >= 1; off >>= 1) m = fmaxf(m, __shfl_down(m, off, 64));
    __shared__ float sm[16];
    if ((threadIdx.x & 63) == 0) sm[threadIdx.x >> 6] = m;
    __syncthreads();
    if (threadIdx.x == 0) {
        float t = sm[0];
        const int nw = blockDim.x >> 6;
        for (int w = 1; w < nw; ++w) t = fmaxf(t, sm[w]);
        maxn[b] = sqrtf(t);
    }
}

__global__ void scatter_kernel(const float* __restrict__ coords,
                               const float* __restrict__ features,
                               const float* __restrict__ mean,
                               const float* __restrict__ maxn,
                               float* __restrict__ out,
                               float* __restrict__ nc_out,
                               float* __restrict__ counts) {
    const int idx = blockIdx.x * blockDim.x + threadIdx.x;
    if (idx >= B_ * N_) return;
    const int b = idx >> 16;
    const int n = idx & (N_ - 1);
    const float* pc = coords + (size_t)b * 3 * N_;
    const float denom = 2.0f * maxn[b];
    int flat = 0;
    #pragma unroll
    for (int a = 0; a < 3; ++a) {
        float v = (pc[(size_t)a * N_ + n] - mean[b * 3 + a]) / denom + 0.5f;
        v = v * (float)Rr;
        v = fminf(fmaxf(v, 0.0f), (float)(Rr - 1));
        nc_out[(size_t)b * 3 * N_ + (size_t)a * N_ + n] = v;
        flat = flat * Rr + (int)rintf(v);
    }
    atomicAdd(&counts[b * R3 + flat], 1.0f);
    const float* pf = features + (size_t)b * C_ * N_ + n;
    float* po = out + (size_t)b * C_ * R3 + flat;
    #pragma unroll 4
    for (int c = 0; c < C_; ++c) atomicAdd(po + (size_t)c * R3, pf[(size_t)c * N_]);
}

__global__ void finalize_kernel(float* __restrict__ out,
                                const float* __restrict__ counts) {
    const int idx = blockIdx.x * blockDim.x + threadIdx.x;
    if (idx >= B_ * C_ * R3) return;
    const int b = idx / (C_ * R3);
    const int v = idx & (R3 - 1);
    out[idx] = out[idx] / fmaxf(counts[b * R3 + v], 1.0f);
}

extern "C" void kernel_launch(void* const* d_in, const int* in_sizes, int n_in,
                              void* d_out, int out_size, void* d_ws, size_t ws_size,
                              hipStream_t stream) {
    const float* features = (const float*)d_in[0];
    const float* coords   = (const float*)d_in[1];

    float* out    = (float*)d_out;
    float* nc_out = out + (size_t)B_ * C_ * R3;

    const size_t accB   = (size_t)B_ * R3 * C_ * sizeof(float);
    const size_t cntB   = (size_t)B_ * R3 * sizeof(int);
    const size_t curB   = cntB;
    const size_t flatB  = (size_t)B_ * N_ * sizeof(int);
    const size_t clistB = (size_t)B_ * R3 * sizeof(int4);
    const size_t smallB = 16384;
    const size_t ftsB   = (size_t)B_ * N_ * C_;

    const size_t need = accB + cntB + curB + flatB + clistB + smallB + ftsB;
    const int pts = B_ * N_;

    if (ws_size >= need) {
        char* w = (char*)d_ws;
        float* acc    = (float*)w;                 w += accB;
        int*   counts = (int*)w;                   w += cntB;
        int*   cursor = (int*)w;                   w += curB;
        int*   flat   = (int*)w;                   w += flatB;
        int4*  clist  = (int4*)w;                  w += clistB;
        int*   n_occ  = (int*)w;
        float* pmean  = (float*)(w + 16);
        float* pmax   = pmean + B_ * 3 * PBLK;
        w += smallB;
        unsigned char* ftS = (unsigned char*)w;

        pmean_zero_kernel<<<B_ * 3 * PBLK + 256, 256, 0, stream>>>(
            coords, pmean, (int4*)counts, n_occ);
        partial_max_kernel<<<B_ * PBLKM, 256, 0, stream>>>(coords, pmean, pmax);
        voxelize_kernel<<<pts / 256, 256, 0, stream>>>(
            coords, pmean, pmax, nc_out, flat, counts);
        scan_compact_kernel<<<B_, 1024, 0, stream>>>(counts, cursor, clist, n_occ);
        sorted_transpose_ids_kernel<<<B_ * (N_ / 64), 256, 0, stream>>>(
            features, flat, cursor, ftS);
        voxel_sum_compact_kernel<<<2048, 256, 0, stream>>>(ftS, clist, n_occ, acc);
        transpose_finalize_kernel<<<B_ * (R3 / 64), 256, 0, stream>>>(acc, counts, out);
    } else {
        float* counts = (float*)d_ws;
        float* mean   = counts + (size_t)B_ * R3;
        float* maxn   = mean + B_ * 3;

        hipMemsetAsync(d_out, 0, (size_t)B_ * C_ * R3 * sizeof(float), stream);
        hipMemsetAsync(d_ws, 0, ((size_t)B_ * R3 + B_ * 3 + B_) * sizeof(float), stream);

        mean_kernel<<<B_ * 3, 256, 0, stream>>>(coords, mean);
        maxnorm_kernel<<<B_, 1024, 0, stream>>>(coords, mean, maxn);
        scatter_kernel<<<(pts + 255) / 256, 256, 0, stream>>>(
            coords, features, mean, maxn, out, nc_out, counts);
        finalize_kernel<<<(B_ * C_ * R3 + 255) / 256, 256, 0, stream>>>(out, counts);
    }
}